// Round 6
// baseline (582.738 us; speedup 1.0000x reference)
//
#include <hip/hip_runtime.h>
#include <cstdint>

// Shapes: B=8, C=256, H=W=64 -> N=4096, d=32, groups=32 (8 ch/group)

typedef __bf16 bf16x8 __attribute__((ext_vector_type(8)));
typedef float f32x4 __attribute__((ext_vector_type(4)));
typedef float f32x16 __attribute__((ext_vector_type(16)));
typedef unsigned int u32x4 __attribute__((ext_vector_type(4)));
typedef unsigned short u16x4 __attribute__((ext_vector_type(4)));
typedef unsigned short u16x8 __attribute__((ext_vector_type(8)));

#define DEVI __device__ __forceinline__

DEVI unsigned short f2bf(float f) {
    __bf16 h = (__bf16)f;               // RNE fptrunc
    return __builtin_bit_cast(unsigned short, h);
}
DEVI float bf2f(unsigned short u) {
    unsigned int x = ((unsigned int)u) << 16;
    return __builtin_bit_cast(float, x);
}

DEVI f32x4 mfma16(bf16x8 a, bf16x8 b, f32x4 c) {
    return __builtin_amdgcn_mfma_f32_16x16x32_bf16(a, b, c, 0, 0, 0);
}
DEVI f32x16 mfma32(bf16x8 a, bf16x8 b, f32x16 c) {
    return __builtin_amdgcn_mfma_f32_32x32x16_bf16(a, b, c, 0, 0, 0);
}

// async global->LDS, 16B per lane, wave-uniform LDS base + lane*16
DEVI void glds16(const unsigned short* g, unsigned short* l) {
    const __attribute__((address_space(1))) unsigned int* gp =
        reinterpret_cast<const __attribute__((address_space(1))) unsigned int*>(
            reinterpret_cast<uintptr_t>(g));
    __attribute__((address_space(3))) unsigned int* lp =
        reinterpret_cast<__attribute__((address_space(3))) unsigned int*>(
            reinterpret_cast<uintptr_t>(l));
    __builtin_amdgcn_global_load_lds(gp, lp, 16, 0, 0);
}

// raw barrier without the compiler's vmcnt(0)-drain; manual waits only
DEVI void barrier_raw() {
    asm volatile("" ::: "memory");
    __builtin_amdgcn_s_barrier();
    asm volatile("" ::: "memory");
}
DEVI void wait_vm0() {
    // SIMM16: vmcnt[3:0]=0, expcnt[6:4]=7, lgkmcnt[13:8]=0x3F, vmcnt[5:4]=0
    __builtin_amdgcn_s_waitcnt(0x3F70);
}

// log2(e)/sqrt(32): folded into Wq so S exits QK-MFMA in exp2 domain
#define QSCALE 0.2550663133f
#define MFIX   12.0f

// ---------------- weight pack fp32 -> bf16 ----------------
__global__ __launch_bounds__(256) void k_pack(
        const float* __restrict__ wq, const float* __restrict__ wk,
        const float* __restrict__ wv, const float* __restrict__ wp,
        unsigned short* __restrict__ bqk, unsigned short* __restrict__ bv,
        unsigned short* __restrict__ bp) {
    int i = blockIdx.x * 256 + threadIdx.x;        // grid 256 -> 65536 threads
    if (i < 8192)       bqk[i] = f2bf(wq[i] * QSCALE);   // rows 0..31 = Wq (pre-scaled)
    else if (i < 16384) bqk[i] = f2bf(wk[i - 8192]);     // rows 32..63 = Wk
    bv[i] = f2bf(wv[i]);
    bp[i] = f2bf(wp[i]);
}

// ---------------- group norm -> h^T (B*N, C) bf16 ----------------
__global__ __launch_bounds__(1024) void k_gnorm(
        const float* __restrict__ x, const float* __restrict__ gw,
        const float* __restrict__ gb, unsigned short* __restrict__ ht) {
    int bg = blockIdx.x;               // 256 blocks = 8 batches * 32 groups
    int b = bg >> 5, g = bg & 31;
    const float* xb = x + ((size_t)(b * 256 + g * 8)) * 4096;  // 8 contiguous rows
    int t = threadIdx.x;
    float s1 = 0.f, s2 = 0.f;
    const f32x4* xv4 = (const f32x4*)xb;
    for (int i = t; i < 8192; i += 1024) {
        f32x4 v = xv4[i];
        #pragma unroll
        for (int j = 0; j < 4; j++) { s1 += v[j]; s2 += v[j] * v[j]; }
    }
    #pragma unroll
    for (int off = 1; off < 64; off <<= 1) {
        s1 += __shfl_xor(s1, off);
        s2 += __shfl_xor(s2, off);
    }
    __shared__ float red[34];
    int wv_ = t >> 6;
    if ((t & 63) == 0) { red[wv_ * 2] = s1; red[wv_ * 2 + 1] = s2; }
    __syncthreads();
    if (t == 0) {
        float a = 0.f, q = 0.f;
        #pragma unroll
        for (int i = 0; i < 16; i++) { a += red[i * 2]; q += red[i * 2 + 1]; }
        float mean = a * (1.f / 32768.f);
        float var = q * (1.f / 32768.f) - mean * mean;
        red[32] = mean; red[33] = rsqrtf(var + 1e-5f);
    }
    __syncthreads();
    float mean = red[32], rstd = red[33];
    float wv8[8], bv8[8];
    #pragma unroll
    for (int c = 0; c < 8; c++) { wv8[c] = gw[g * 8 + c] * rstd; bv8[c] = gb[g * 8 + c] - mean * rstd * gw[g * 8 + c]; }
    int n0 = t * 4;
    f32x4 cv[8];
    #pragma unroll
    for (int c = 0; c < 8; c++) cv[c] = *(const f32x4*)(xb + c * 4096 + n0);
    #pragma unroll
    for (int j = 0; j < 4; j++) {
        u16x8 pk;
        #pragma unroll
        for (int c = 0; c < 8; c++) pk[c] = f2bf(cv[c][j] * wv8[c] + bv8[c]);
        *(u16x8*)(&ht[((size_t)(b * 4096 + n0 + j)) * 256 + g * 8]) = pk;  // 16B store
    }
}

// ---------------- GEMM  C[M x Ncols] = A[M x 256] * Bw[Ncols x 256]^T ----------------
// EPI 0: bf16 row-major out (ldout).  EPI 1: bf16 transposed Vt[b][o][n] with
//        key-dim bit2<->bit3 swap per 16-group (PV A-frag permutation).
// EPI 2: fp32 transposed + residual: out[b][o][n] = x + gamma*acc.
template <int EPI>
__global__ __launch_bounds__(256) void k_gemm(
        const unsigned short* __restrict__ A, const unsigned short* __restrict__ Bw,
        void* __restrict__ outp, const float* __restrict__ xres,
        const float* __restrict__ gamma, int ldout) {
    __shared__ unsigned short lA[128 * 72];
    __shared__ unsigned short lB[64 * 72];
    int t = threadIdx.x;
    int m0 = blockIdx.x * 128, n0 = blockIdx.y * 64;
    int w = t >> 6, lane = t & 63, l15 = lane & 15, quad = lane >> 4;
    f32x4 z4 = {0.f, 0.f, 0.f, 0.f};
    f32x4 acc[2][4];
    #pragma unroll
    for (int i = 0; i < 2; i++)
        #pragma unroll
        for (int j = 0; j < 4; j++) acc[i][j] = z4;

    for (int kb = 0; kb < 4; kb++) {
        #pragma unroll
        for (int i = 0; i < 4; i++) {
            int ch = i * 256 + t;
            int row = ch >> 3, col = (ch & 7) * 8;
            u32x4 v = *(const u32x4*)(A + (size_t)(m0 + row) * 256 + kb * 64 + col);
            *(u32x4*)(&lA[row * 72 + col]) = v;
        }
        #pragma unroll
        for (int i = 0; i < 2; i++) {
            int ch = i * 256 + t;
            int row = ch >> 3, col = (ch & 7) * 8;
            u32x4 v = *(const u32x4*)(Bw + (size_t)(n0 + row) * 256 + kb * 64 + col);
            *(u32x4*)(&lB[row * 72 + col]) = v;
        }
        __syncthreads();
        #pragma unroll
        for (int ks = 0; ks < 2; ks++) {
            bf16x8 af[2], bfr[4];
            #pragma unroll
            for (int fr = 0; fr < 2; fr++)
                af[fr] = *(const bf16x8*)(&lA[(w * 32 + fr * 16 + l15) * 72 + ks * 32 + quad * 8]);
            #pragma unroll
            for (int fn = 0; fn < 4; fn++)
                bfr[fn] = *(const bf16x8*)(&lB[(fn * 16 + l15) * 72 + ks * 32 + quad * 8]);
            #pragma unroll
            for (int fr = 0; fr < 2; fr++)
                #pragma unroll
                for (int fn = 0; fn < 4; fn++)
                    acc[fr][fn] = mfma16(af[fr], bfr[fn], acc[fr][fn]);
        }
        __syncthreads();
    }

    if (EPI == 0) {
        unsigned short* out = (unsigned short*)outp;
        #pragma unroll
        for (int fr = 0; fr < 2; fr++)
            #pragma unroll
            for (int fn = 0; fn < 4; fn++)
                #pragma unroll
                for (int r = 0; r < 4; r++) {
                    int m = m0 + w * 32 + fr * 16 + quad * 4 + r;
                    int n = n0 + fn * 16 + l15;
                    out[(size_t)m * ldout + n] = f2bf(acc[fr][fn][r]);
                }
    } else if (EPI == 1) {
        unsigned short* out = (unsigned short*)outp;
        int b = m0 >> 12, nb = (m0 & 4095) + w * 32;
        int swq = ((quad & 1) << 1) | (quad >> 1);   // bit2<->bit3 swap of n within 16
        #pragma unroll
        for (int fr = 0; fr < 2; fr++)
            #pragma unroll
            for (int fn = 0; fn < 4; fn++) {
                int o = n0 + fn * 16 + l15;
                int n = nb + fr * 16 + swq * 4;
                u16x4 pk;
                #pragma unroll
                for (int r = 0; r < 4; r++) pk[r] = f2bf(acc[fr][fn][r]);
                *(u16x4*)(&out[(((size_t)(b * 256 + o)) << 12) + n]) = pk;
            }
    } else {
        float* out = (float*)outp;
        float gm = gamma[0];
        int b = m0 >> 12, nb = (m0 & 4095) + w * 32;
        #pragma unroll
        for (int fr = 0; fr < 2; fr++)
            #pragma unroll
            for (int fn = 0; fn < 4; fn++) {
                int o = n0 + fn * 16 + l15;
                int n = nb + fr * 16 + quad * 4;
                size_t base = (((size_t)(b * 256 + o)) << 12) + n;
                f32x4 xv = *(const f32x4*)(xres + base);
                f32x4 ov;
                #pragma unroll
                for (int r = 0; r < 4; r++) ov[r] = xv[r] + gm * acc[fr][fn][r];
                *(f32x4*)(out + base) = ov;
            }
    }
}

// ---------------- flash attention: 32x32 MFMA, dbuf, 2-way q register-blocking --
// QK: (B*N, 64) bf16 (q cols 0..31 pre-scaled, k cols 32..63).
// Vt: (B, 256, N) bf16, key-dim sigma-permuted (bit2<->bit3 per 16-group).
// Block: 128 q-rows, 4 waves = 2 qh x 2 kh; each wave owns TWO 32-q tiles so
// every V b128 read feeds 2 MFMAs. Grid 256 = 1 block/CU. Oacc = 256 VGPR.
__global__ __launch_bounds__(256, 1) void k_flash(
        const unsigned short* __restrict__ QK, const unsigned short* __restrict__ Vt,
        unsigned short* __restrict__ Oa) {
    __shared__ __align__(16) char smem[81920];   // 2 x (4KB K + 32KB V); 80KB epilogue
    int id = blockIdx.x;
    int b = id & 7, qt = id >> 3;      // batch <-> XCD affinity
    int t = threadIdx.x, w = t >> 6, ln = t & 63;
    int l31 = ln & 31, h = ln >> 5;
    int qh = w >> 1, kh = w & 1;
    int q0 = qt * 128 + qh * 64;       // this wave's 64-q range (2 tiles of 32)

    // persistent Q B-frags: B[k=d][n=q]; lane: q=l31, d = s*16 + h*8 + j
    bf16x8 qb0[2], qb1[2];
    #pragma unroll
    for (int qt2 = 0; qt2 < 2; qt2++) {
        const unsigned short* qrow = QK + ((size_t)(b * 4096 + q0 + qt2 * 32 + l31)) * 64;
        qb0[qt2] = *(const bf16x8*)(qrow + h * 8);
        qb1[qt2] = *(const bf16x8*)(qrow + 16 + h * 8);
    }

    // staging: K tile (wave w stages keys w*16..+16), chunk-swizzled for A-frag reads
    int cgK = (ln & 3) ^ ((ln >> 2) & 3) ^ ((ln >> 4) & 3);
    const unsigned short* gK = QK + ((size_t)(b * 4096 + w * 16 + (ln >> 2))) * 64 + 32 + cgK * 8;
    // V tile: wave w stages o-rows w*64..+64, chunk-swizzled (slot = chunk ^ (o&7))
    int vc8 = (ln & 7) ^ ((ln >> 3) & 7);
    const unsigned short* gV = Vt + (((size_t)(b * 256 + w * 64 + (ln >> 3))) << 12) + vc8 * 8;

    // double buffers
    unsigned short* lK0 = (unsigned short*)smem;
    unsigned short* lV0 = (unsigned short*)(smem + 4096);
    unsigned short* lK1 = (unsigned short*)(smem + 36864);
    unsigned short* lV1 = (unsigned short*)(smem + 36864 + 4096);
    unsigned short* sK0 = lK0 + w * 512;
    unsigned short* sV0 = lV0 + w * 4096;
    unsigned short* sK1 = lK1 + w * 512;
    unsigned short* sV1 = lV1 + w * 4096;

    u16x8 onesu = {0x3F80, 0x3F80, 0x3F80, 0x3F80, 0x3F80, 0x3F80, 0x3F80, 0x3F80};
    bf16x8 ones = __builtin_bit_cast(bf16x8, onesu);
    f32x16 z16;
    #pragma unroll
    for (int i = 0; i < 16; i++) z16[i] = 0.f;
    f32x16 minit;
    #pragma unroll
    for (int i = 0; i < 16; i++) minit[i] = -MFIX;
    f32x16 Oacc[2][8];
    #pragma unroll
    for (int qt2 = 0; qt2 < 2; qt2++)
        #pragma unroll
        for (int i = 0; i < 8; i++) Oacc[qt2][i] = z16;
    f32x16 lacc[2] = {z16, z16};

    // loop-invariant LDS read offsets
    int gl = (l31 & 3) ^ ((l31 >> 2) & 3);
    const unsigned short* kf0p0 = lK0 + (kh * 32 + l31) * 32 + ((0 + h) ^ gl) * 8;
    const unsigned short* kf1p0 = lK0 + (kh * 32 + l31) * 32 + ((2 + h) ^ gl) * 8;
    const unsigned short* kf0p1 = lK1 + (kh * 32 + l31) * 32 + ((0 + h) ^ gl) * 8;
    const unsigned short* kf1p1 = lK1 + (kh * 32 + l31) * 32 + ((2 + h) ^ gl) * 8;
    int slotA = ((kh * 4 + 0 * 2 + h) ^ (ln & 7)) * 8;
    int slotB = ((kh * 4 + 1 * 2 + h) ^ (ln & 7)) * 8;

    auto stage = [&](int kn, unsigned short* sK, unsigned short* sV) {
        glds16(gK + (size_t)kn * 4096, sK);
        #pragma unroll
        for (int j = 0; j < 8; j++)
            glds16(gV + ((size_t)j * 8 << 12) + kn * 64, sV + j * 512);
    };

    auto compute = [&](const unsigned short* kf0p, const unsigned short* kf1p,
                       const unsigned short* lV) {
        bf16x8 kf0 = *(const bf16x8*)kf0p;
        bf16x8 kf1 = *(const bf16x8*)kf1p;
        bf16x8 pa[2][2];
        #pragma unroll
        for (int qt2 = 0; qt2 < 2; qt2++) {
            f32x16 St = mfma32(kf0, qb0[qt2], minit);
            St = mfma32(kf1, qb1[qt2], St);
            u16x8 p0u, p1u;
            #pragma unroll
            for (int j = 0; j < 8; j++) {
                p0u[j] = f2bf(__builtin_amdgcn_exp2f(St[j]));
                p1u[j] = f2bf(__builtin_amdgcn_exp2f(St[8 + j]));
            }
            pa[qt2][0] = __builtin_bit_cast(bf16x8, p0u);
            pa[qt2][1] = __builtin_bit_cast(bf16x8, p1u);
            lacc[qt2] = mfma32(pa[qt2][0], ones, lacc[qt2]);
            lacc[qt2] = mfma32(pa[qt2][1], ones, lacc[qt2]);
        }
        #pragma unroll
        for (int nt = 0; nt < 8; nt++) {
            bf16x8 vf = *(const bf16x8*)(lV + (nt * 32 + l31) * 64 + slotA);
            Oacc[0][nt] = mfma32(pa[0][0], vf, Oacc[0][nt]);
            Oacc[1][nt] = mfma32(pa[1][0], vf, Oacc[1][nt]);
        }
        #pragma unroll
        for (int nt = 0; nt < 8; nt++) {
            bf16x8 vf = *(const bf16x8*)(lV + (nt * 32 + l31) * 64 + slotB);
            Oacc[0][nt] = mfma32(pa[0][1], vf, Oacc[0][nt]);
            Oacc[1][nt] = mfma32(pa[1][1], vf, Oacc[1][nt]);
        }
    };

    stage(0, sK0, sV0);                 // preload tile 0 into buf0
    for (int kt = 0; kt < 64; kt += 2) {
        // --- even tile: compute buf0, prefetch kt+1 into buf1 ---
        wait_vm0();                     // drain buf0's loads (issued 1 iter ago)
        barrier_raw();
        stage(kt + 1, sK1, sV1);
        compute(kf0p0, kf1p0, lV0);
        // --- odd tile: compute buf1, prefetch kt+2 into buf0 ---
        wait_vm0();
        barrier_raw();
        if (kt + 2 < 64) stage(kt + 2, sK0, sV0);
        compute(kf0p1, kf1p1, lV1);
    }
    __syncthreads();                    // all reads done before smem reuse

    // ---- cross-wave (key-half) combine via smem; kh=1 publishes, kh=0 reduces ----
    if (kh == 1) {
        #pragma unroll
        for (int qt2 = 0; qt2 < 2; qt2++) {
            #pragma unroll
            for (int nt = 0; nt < 8; nt++)
                #pragma unroll
                for (int rg = 0; rg < 2; rg++) {
                    u16x8 pk;
                    #pragma unroll
                    for (int j = 0; j < 8; j++) pk[j] = f2bf(Oacc[qt2][nt][rg * 8 + j]);
                    *(u16x8*)(smem + qh * 32768 + qt2 * 16384 + nt * 2048 + rg * 1024 + ln * 16) = pk;
                }
            #pragma unroll
            for (int rg = 0; rg < 4; rg++) {
                f32x4 lv;
                #pragma unroll
                for (int j = 0; j < 4; j++) lv[j] = lacc[qt2][rg * 4 + j];
                *(f32x4*)(smem + 65536 + qh * 8192 + qt2 * 4096 + rg * 1024 + ln * 16) = lv;
            }
        }
    }
    __syncthreads();
    if (kh == 0) {
        #pragma unroll
        for (int qt2 = 0; qt2 < 2; qt2++) {
            float rl[16];
            #pragma unroll
            for (int rg = 0; rg < 4; rg++) {
                f32x4 lv = *(const f32x4*)(smem + 65536 + qh * 8192 + qt2 * 4096 + rg * 1024 + ln * 16);
                #pragma unroll
                for (int j = 0; j < 4; j++) rl[rg * 4 + j] = 1.f / (lacc[qt2][rg * 4 + j] + lv[j]);
            }
            size_t rb = (size_t)(b * 4096 + qt * 128 + qh * 64 + qt2 * 32);
            #pragma unroll
            for (int nt = 0; nt < 8; nt++)
                #pragma unroll
                for (int rg = 0; rg < 2; rg++) {
                    u16x8 pk = *(const u16x8*)(smem + qh * 32768 + qt2 * 16384 + nt * 2048 + rg * 1024 + ln * 16);
                    #pragma unroll
                    for (int j = 0; j < 8; j++) {
                        int r = rg * 8 + j;
                        float val = (Oacc[qt2][nt][r] + bf2f(pk[j])) * rl[r];
                        int row = (r & 3) + 8 * (r >> 2) + 4 * h;
                        Oa[(rb + row) * 256 + nt * 32 + l31] = f2bf(val);
                    }
                }
        }
    }
}

// ---------------- launch ----------------
extern "C" void kernel_launch(void* const* d_in, const int* in_sizes, int n_in,
                              void* d_out, int out_size, void* d_ws, size_t ws_size,
                              hipStream_t stream) {
    const float* x  = (const float*)d_in[0];
    const float* nw = (const float*)d_in[1];
    const float* nb = (const float*)d_in[2];
    const float* wq = (const float*)d_in[3];
    const float* wk = (const float*)d_in[4];
    const float* wv = (const float*)d_in[5];
    const float* wp = (const float*)d_in[6];
    const float* gm = (const float*)d_in[7];

    char* p = (char*)d_ws;
    unsigned short* ht  = (unsigned short*)p; p += (size_t)32768 * 256 * 2;  // 16 MB
    unsigned short* qk  = (unsigned short*)p; p += (size_t)32768 * 64 * 2;   // 4 MB
    unsigned short* vt  = (unsigned short*)p; p += (size_t)8 * 256 * 4096 * 2; // 16 MB
    unsigned short* oa  = (unsigned short*)p; p += (size_t)32768 * 256 * 2;  // 16 MB
    unsigned short* bqk = (unsigned short*)p; p += 64 * 256 * 2;
    unsigned short* bv  = (unsigned short*)p; p += 256 * 256 * 2;
    unsigned short* bp  = (unsigned short*)p; p += 256 * 256 * 2;

    k_pack<<<dim3(256), dim3(256), 0, stream>>>(wq, wk, wv, wp, bqk, bv, bp);
    k_gnorm<<<dim3(256), dim3(1024), 0, stream>>>(x, nw, nb, ht);
    k_gemm<0><<<dim3(256, 1), dim3(256), 0, stream>>>(ht, bqk, (void*)qk, nullptr, nullptr, 64);
    k_gemm<1><<<dim3(256, 4), dim3(256), 0, stream>>>(ht, bv, (void*)vt, nullptr, nullptr, 0);
    k_flash<<<dim3(256), dim3(256), 0, stream>>>(qk, vt, oa);
    k_gemm<2><<<dim3(256, 4), dim3(256), 0, stream>>>(oa, bp, d_out, x, gm, 0);
}

// Round 7
// 252.304 us; speedup vs baseline: 2.3097x; 2.3097x over previous
//
#include <hip/hip_runtime.h>
#include <cstdint>

// Shapes: B=8, C=256, H=W=64 -> N=4096, d=32, groups=32 (8 ch/group)

typedef __bf16 bf16x8 __attribute__((ext_vector_type(8)));
typedef float f32x4 __attribute__((ext_vector_type(4)));
typedef float f32x16 __attribute__((ext_vector_type(16)));
typedef unsigned int u32x4 __attribute__((ext_vector_type(4)));
typedef unsigned short u16x4 __attribute__((ext_vector_type(4)));
typedef unsigned short u16x8 __attribute__((ext_vector_type(8)));

#define DEVI __device__ __forceinline__

DEVI unsigned short f2bf(float f) {
    __bf16 h = (__bf16)f;               // RNE fptrunc
    return __builtin_bit_cast(unsigned short, h);
}
DEVI float bf2f(unsigned short u) {
    unsigned int x = ((unsigned int)u) << 16;
    return __builtin_bit_cast(float, x);
}

DEVI f32x4 mfma16(bf16x8 a, bf16x8 b, f32x4 c) {
    return __builtin_amdgcn_mfma_f32_16x16x32_bf16(a, b, c, 0, 0, 0);
}
DEVI f32x16 mfma32(bf16x8 a, bf16x8 b, f32x16 c) {
    return __builtin_amdgcn_mfma_f32_32x32x16_bf16(a, b, c, 0, 0, 0);
}

// async global->LDS, 16B per lane, wave-uniform LDS base + lane*16
DEVI void glds16(const unsigned short* g, unsigned short* l) {
    const __attribute__((address_space(1))) unsigned int* gp =
        reinterpret_cast<const __attribute__((address_space(1))) unsigned int*>(
            reinterpret_cast<uintptr_t>(g));
    __attribute__((address_space(3))) unsigned int* lp =
        reinterpret_cast<__attribute__((address_space(3))) unsigned int*>(
            reinterpret_cast<uintptr_t>(l));
    __builtin_amdgcn_global_load_lds(gp, lp, 16, 0, 0);
}

// raw barrier without the compiler's vmcnt(0)-drain; manual waits only
DEVI void barrier_raw() {
    asm volatile("" ::: "memory");
    __builtin_amdgcn_s_barrier();
    asm volatile("" ::: "memory");
}
DEVI void wait_vm0() {
    // SIMM16: vmcnt[3:0]=0, expcnt[6:4]=7, lgkmcnt[13:8]=0x3F, vmcnt[5:4]=0
    __builtin_amdgcn_s_waitcnt(0x3F70);
}

// log2(e)/sqrt(32): folded into Wq so S exits QK-MFMA in exp2 domain
#define QSCALE 0.2550663133f
#define MFIX   12.0f

// ---------------- weight pack fp32 -> bf16 ----------------
__global__ __launch_bounds__(256) void k_pack(
        const float* __restrict__ wq, const float* __restrict__ wk,
        const float* __restrict__ wv, const float* __restrict__ wp,
        unsigned short* __restrict__ bqk, unsigned short* __restrict__ bv,
        unsigned short* __restrict__ bp) {
    int i = blockIdx.x * 256 + threadIdx.x;        // grid 256 -> 65536 threads
    if (i < 8192)       bqk[i] = f2bf(wq[i] * QSCALE);   // rows 0..31 = Wq (pre-scaled)
    else if (i < 16384) bqk[i] = f2bf(wk[i - 8192]);     // rows 32..63 = Wk
    bv[i] = f2bf(wv[i]);
    bp[i] = f2bf(wp[i]);
}

// ---------------- group norm -> h^T (B*N, C) bf16 ----------------
__global__ __launch_bounds__(1024) void k_gnorm(
        const float* __restrict__ x, const float* __restrict__ gw,
        const float* __restrict__ gb, unsigned short* __restrict__ ht) {
    int bg = blockIdx.x;               // 256 blocks = 8 batches * 32 groups
    int b = bg >> 5, g = bg & 31;
    const float* xb = x + ((size_t)(b * 256 + g * 8)) * 4096;  // 8 contiguous rows
    int t = threadIdx.x;
    float s1 = 0.f, s2 = 0.f;
    const f32x4* xv4 = (const f32x4*)xb;
    for (int i = t; i < 8192; i += 1024) {
        f32x4 v = xv4[i];
        #pragma unroll
        for (int j = 0; j < 4; j++) { s1 += v[j]; s2 += v[j] * v[j]; }
    }
    #pragma unroll
    for (int off = 1; off < 64; off <<= 1) {
        s1 += __shfl_xor(s1, off);
        s2 += __shfl_xor(s2, off);
    }
    __shared__ float red[34];
    int wv_ = t >> 6;
    if ((t & 63) == 0) { red[wv_ * 2] = s1; red[wv_ * 2 + 1] = s2; }
    __syncthreads();
    if (t == 0) {
        float a = 0.f, q = 0.f;
        #pragma unroll
        for (int i = 0; i < 16; i++) { a += red[i * 2]; q += red[i * 2 + 1]; }
        float mean = a * (1.f / 32768.f);
        float var = q * (1.f / 32768.f) - mean * mean;
        red[32] = mean; red[33] = rsqrtf(var + 1e-5f);
    }
    __syncthreads();
    float mean = red[32], rstd = red[33];
    float wv8[8], bv8[8];
    #pragma unroll
    for (int c = 0; c < 8; c++) { wv8[c] = gw[g * 8 + c] * rstd; bv8[c] = gb[g * 8 + c] - mean * rstd * gw[g * 8 + c]; }
    int n0 = t * 4;
    f32x4 cv[8];
    #pragma unroll
    for (int c = 0; c < 8; c++) cv[c] = *(const f32x4*)(xb + c * 4096 + n0);
    #pragma unroll
    for (int j = 0; j < 4; j++) {
        u16x8 pk;
        #pragma unroll
        for (int c = 0; c < 8; c++) pk[c] = f2bf(cv[c][j] * wv8[c] + bv8[c]);
        *(u16x8*)(&ht[((size_t)(b * 4096 + n0 + j)) * 256 + g * 8]) = pk;  // 16B store
    }
}

// ---------------- GEMM  C[M x Ncols] = A[M x 256] * Bw[Ncols x 256]^T ----------------
// EPI 0: bf16 row-major out (ldout).  EPI 1: bf16 transposed Vt[b][o][n] with
//        key-dim bit2<->bit3 swap per 16-group (PV A-frag permutation).
// EPI 2: fp32 transposed + residual: out[b][o][n] = x + gamma*acc.
template <int EPI>
__global__ __launch_bounds__(256) void k_gemm(
        const unsigned short* __restrict__ A, const unsigned short* __restrict__ Bw,
        void* __restrict__ outp, const float* __restrict__ xres,
        const float* __restrict__ gamma, int ldout) {
    __shared__ unsigned short lA[128 * 72];
    __shared__ unsigned short lB[64 * 72];
    int t = threadIdx.x;
    int m0 = blockIdx.x * 128, n0 = blockIdx.y * 64;
    int w = t >> 6, lane = t & 63, l15 = lane & 15, quad = lane >> 4;
    f32x4 z4 = {0.f, 0.f, 0.f, 0.f};
    f32x4 acc[2][4];
    #pragma unroll
    for (int i = 0; i < 2; i++)
        #pragma unroll
        for (int j = 0; j < 4; j++) acc[i][j] = z4;

    for (int kb = 0; kb < 4; kb++) {
        #pragma unroll
        for (int i = 0; i < 4; i++) {
            int ch = i * 256 + t;
            int row = ch >> 3, col = (ch & 7) * 8;
            u32x4 v = *(const u32x4*)(A + (size_t)(m0 + row) * 256 + kb * 64 + col);
            *(u32x4*)(&lA[row * 72 + col]) = v;
        }
        #pragma unroll
        for (int i = 0; i < 2; i++) {
            int ch = i * 256 + t;
            int row = ch >> 3, col = (ch & 7) * 8;
            u32x4 v = *(const u32x4*)(Bw + (size_t)(n0 + row) * 256 + kb * 64 + col);
            *(u32x4*)(&lB[row * 72 + col]) = v;
        }
        __syncthreads();
        #pragma unroll
        for (int ks = 0; ks < 2; ks++) {
            bf16x8 af[2], bfr[4];
            #pragma unroll
            for (int fr = 0; fr < 2; fr++)
                af[fr] = *(const bf16x8*)(&lA[(w * 32 + fr * 16 + l15) * 72 + ks * 32 + quad * 8]);
            #pragma unroll
            for (int fn = 0; fn < 4; fn++)
                bfr[fn] = *(const bf16x8*)(&lB[(fn * 16 + l15) * 72 + ks * 32 + quad * 8]);
            #pragma unroll
            for (int fr = 0; fr < 2; fr++)
                #pragma unroll
                for (int fn = 0; fn < 4; fn++)
                    acc[fr][fn] = mfma16(af[fr], bfr[fn], acc[fr][fn]);
        }
        __syncthreads();
    }

    if (EPI == 0) {
        unsigned short* out = (unsigned short*)outp;
        #pragma unroll
        for (int fr = 0; fr < 2; fr++)
            #pragma unroll
            for (int fn = 0; fn < 4; fn++)
                #pragma unroll
                for (int r = 0; r < 4; r++) {
                    int m = m0 + w * 32 + fr * 16 + quad * 4 + r;
                    int n = n0 + fn * 16 + l15;
                    out[(size_t)m * ldout + n] = f2bf(acc[fr][fn][r]);
                }
    } else if (EPI == 1) {
        unsigned short* out = (unsigned short*)outp;
        int b = m0 >> 12, nb = (m0 & 4095) + w * 32;
        int swq = ((quad & 1) << 1) | (quad >> 1);   // bit2<->bit3 swap of n within 16
        #pragma unroll
        for (int fr = 0; fr < 2; fr++)
            #pragma unroll
            for (int fn = 0; fn < 4; fn++) {
                int o = n0 + fn * 16 + l15;
                int n = nb + fr * 16 + swq * 4;
                u16x4 pk;
                #pragma unroll
                for (int r = 0; r < 4; r++) pk[r] = f2bf(acc[fr][fn][r]);
                *(u16x4*)(&out[(((size_t)(b * 256 + o)) << 12) + n]) = pk;
            }
    } else {
        float* out = (float*)outp;
        float gm = gamma[0];
        int b = m0 >> 12, nb = (m0 & 4095) + w * 32;
        #pragma unroll
        for (int fr = 0; fr < 2; fr++)
            #pragma unroll
            for (int fn = 0; fn < 4; fn++) {
                int o = n0 + fn * 16 + l15;
                int n = nb + fr * 16 + quad * 4;
                size_t base = (((size_t)(b * 256 + o)) << 12) + n;
                f32x4 xv = *(const f32x4*)(xres + base);
                f32x4 ov;
                #pragma unroll
                for (int r = 0; r < 4; r++) ov[r] = xv[r] + gm * acc[fr][fn][r];
                *(f32x4*)(out + base) = ov;
            }
    }
}

// ---------------- flash attention: 32x32 MFMA, dbuf, q x2 reg-block, o-split ----
// QK: (B*N, 64) bf16 (q cols 0..31 pre-scaled, k cols 32..63).
// Vt: (B, 256, N) bf16, key-dim sigma-permuted (bit2<->bit3 per 16-group).
// Grid 512 = 8 b x 32 qblk(128q) x 2 oh(128 o-chans). 4 waves = 2 qh x 2 kh;
// each wave: 2 q-tiles (reg-blocked: every V b128 read feeds 2 MFMAs) x
// 4 o-tiles x its kh. Acc = Oacc[2][4]+lacc[2] = 160 regs (R5's proven
// regime; R6's 288 spilled). 1 block/CU, MFMA-bound: 24 mfma32/wave/tile
// (~775 cyc/SIMD) vs ~60KB LDS/CU-tile (~470 cyc).
__global__ __launch_bounds__(256, 1) void k_flash(
        const unsigned short* __restrict__ QK, const unsigned short* __restrict__ Vt,
        unsigned short* __restrict__ Oa) {
    __shared__ __align__(16) char smem[49152];   // staging 2x20KB; epilogue 48KB
    int id = blockIdx.x;
    int b = id & 7;                    // batch <-> XCD affinity
    int r3 = id >> 3;
    int oh = r3 & 1, qblk = r3 >> 1;   // o-half, q-block(128)
    int t = threadIdx.x, w = t >> 6, ln = t & 63;
    int l31 = ln & 31, h = ln >> 5;
    int qh = w >> 1, kh = w & 1;
    int q0 = qblk * 128 + qh * 64;     // this wave's 64-q range (2 tiles of 32)

    // persistent Q B-frags: B[k=d][n=q]; lane: q=l31, d = s*16 + h*8 + j
    bf16x8 qb0[2], qb1[2];
    #pragma unroll
    for (int qt2 = 0; qt2 < 2; qt2++) {
        const unsigned short* qrow = QK + ((size_t)(b * 4096 + q0 + qt2 * 32 + l31)) * 64;
        qb0[qt2] = *(const bf16x8*)(qrow + h * 8);
        qb1[qt2] = *(const bf16x8*)(qrow + 16 + h * 8);
    }

    // staging: K tile (wave w stages keys w*16..+16), chunk-swizzled for A-frag reads
    int cgK = (ln & 3) ^ ((ln >> 2) & 3) ^ ((ln >> 4) & 3);
    const unsigned short* gK = QK + ((size_t)(b * 4096 + w * 16 + (ln >> 2))) * 64 + 32 + cgK * 8;
    // V half-tile: wave w stages o-rows oh*128 + w*32..+32, chunk-swizzled
    int vc8 = (ln & 7) ^ ((ln >> 3) & 7);
    const unsigned short* gV = Vt + (((size_t)(b * 256 + oh * 128 + w * 32 + (ln >> 3))) << 12) + vc8 * 8;

    // double buffers: K 4KB + V 16KB each
    unsigned short* lK0 = (unsigned short*)smem;
    unsigned short* lV0 = (unsigned short*)(smem + 4096);
    unsigned short* lK1 = (unsigned short*)(smem + 20480);
    unsigned short* lV1 = (unsigned short*)(smem + 24576);
    unsigned short* sK0 = lK0 + w * 512;
    unsigned short* sV0 = lV0 + w * 2048;
    unsigned short* sK1 = lK1 + w * 512;
    unsigned short* sV1 = lV1 + w * 2048;

    u16x8 onesu = {0x3F80, 0x3F80, 0x3F80, 0x3F80, 0x3F80, 0x3F80, 0x3F80, 0x3F80};
    bf16x8 ones = __builtin_bit_cast(bf16x8, onesu);
    f32x16 z16;
    #pragma unroll
    for (int i = 0; i < 16; i++) z16[i] = 0.f;
    f32x16 minit;
    #pragma unroll
    for (int i = 0; i < 16; i++) minit[i] = -MFIX;
    f32x16 Oacc[2][4];
    #pragma unroll
    for (int qt2 = 0; qt2 < 2; qt2++)
        #pragma unroll
        for (int i = 0; i < 4; i++) Oacc[qt2][i] = z16;
    f32x16 lacc[2] = {z16, z16};

    // loop-invariant LDS read offsets
    int gl = (l31 & 3) ^ ((l31 >> 2) & 3);
    const unsigned short* kf0p0 = lK0 + (kh * 32 + l31) * 32 + ((0 + h) ^ gl) * 8;
    const unsigned short* kf1p0 = lK0 + (kh * 32 + l31) * 32 + ((2 + h) ^ gl) * 8;
    const unsigned short* kf0p1 = lK1 + (kh * 32 + l31) * 32 + ((0 + h) ^ gl) * 8;
    const unsigned short* kf1p1 = lK1 + (kh * 32 + l31) * 32 + ((2 + h) ^ gl) * 8;
    int slotA = ((kh * 4 + 0 * 2 + h) ^ (ln & 7)) * 8;
    int slotB = ((kh * 4 + 1 * 2 + h) ^ (ln & 7)) * 8;

    auto stage = [&](int kn, unsigned short* sK, unsigned short* sV) {
        glds16(gK + (size_t)kn * 4096, sK);
        #pragma unroll
        for (int j = 0; j < 4; j++)
            glds16(gV + ((size_t)j * 8 << 12) + kn * 64, sV + j * 512);
    };

    auto compute = [&](const unsigned short* kf0p, const unsigned short* kf1p,
                       const unsigned short* lV) {
        bf16x8 kf0 = *(const bf16x8*)kf0p;
        bf16x8 kf1 = *(const bf16x8*)kf1p;
        bf16x8 pa[2][2];
        #pragma unroll
        for (int qt2 = 0; qt2 < 2; qt2++) {
            f32x16 St = mfma32(kf0, qb0[qt2], minit);
            St = mfma32(kf1, qb1[qt2], St);
            u16x8 p0u, p1u;
            #pragma unroll
            for (int j = 0; j < 8; j++) {
                p0u[j] = f2bf(__builtin_amdgcn_exp2f(St[j]));
                p1u[j] = f2bf(__builtin_amdgcn_exp2f(St[8 + j]));
            }
            pa[qt2][0] = __builtin_bit_cast(bf16x8, p0u);
            pa[qt2][1] = __builtin_bit_cast(bf16x8, p1u);
            lacc[qt2] = mfma32(pa[qt2][0], ones, lacc[qt2]);
            lacc[qt2] = mfma32(pa[qt2][1], ones, lacc[qt2]);
        }
        #pragma unroll
        for (int nt = 0; nt < 4; nt++) {
            bf16x8 vf = *(const bf16x8*)(lV + (nt * 32 + l31) * 64 + slotA);
            Oacc[0][nt] = mfma32(pa[0][0], vf, Oacc[0][nt]);
            Oacc[1][nt] = mfma32(pa[1][0], vf, Oacc[1][nt]);
        }
        #pragma unroll
        for (int nt = 0; nt < 4; nt++) {
            bf16x8 vf = *(const bf16x8*)(lV + (nt * 32 + l31) * 64 + slotB);
            Oacc[0][nt] = mfma32(pa[0][1], vf, Oacc[0][nt]);
            Oacc[1][nt] = mfma32(pa[1][1], vf, Oacc[1][nt]);
        }
    };

    stage(0, sK0, sV0);                 // preload tile 0 into buf0
    for (int kt = 0; kt < 64; kt += 2) {
        // --- even tile: compute buf0, prefetch kt+1 into buf1 ---
        wait_vm0();                     // drain buf0's loads (issued 1 iter ago)
        barrier_raw();
        stage(kt + 1, sK1, sV1);
        compute(kf0p0, kf1p0, lV0);
        // --- odd tile: compute buf1, prefetch kt+2 into buf0 ---
        wait_vm0();
        barrier_raw();
        if (kt + 2 < 64) stage(kt + 2, sK0, sV0);
        compute(kf0p1, kf1p1, lV1);
    }
    __syncthreads();                    // all reads done before smem reuse

    // ---- cross-wave (key-half) combine via smem; kh=1 publishes, kh=0 reduces ----
    if (kh == 1) {
        #pragma unroll
        for (int qt2 = 0; qt2 < 2; qt2++) {
            #pragma unroll
            for (int nt = 0; nt < 4; nt++)
                #pragma unroll
                for (int rg = 0; rg < 2; rg++) {
                    u16x8 pk;
                    #pragma unroll
                    for (int j = 0; j < 8; j++) pk[j] = f2bf(Oacc[qt2][nt][rg * 8 + j]);
                    *(u16x8*)(smem + qh * 16384 + qt2 * 8192 + nt * 2048 + rg * 1024 + ln * 16) = pk;
                }
            #pragma unroll
            for (int rg = 0; rg < 4; rg++) {
                f32x4 lv;
                #pragma unroll
                for (int j = 0; j < 4; j++) lv[j] = lacc[qt2][rg * 4 + j];
                *(f32x4*)(smem + 32768 + qh * 8192 + qt2 * 4096 + rg * 1024 + ln * 16) = lv;
            }
        }
    }
    __syncthreads();
    if (kh == 0) {
        #pragma unroll
        for (int qt2 = 0; qt2 < 2; qt2++) {
            float rl[16];
            #pragma unroll
            for (int rg = 0; rg < 4; rg++) {
                f32x4 lv = *(const f32x4*)(smem + 32768 + qh * 8192 + qt2 * 4096 + rg * 1024 + ln * 16);
                #pragma unroll
                for (int j = 0; j < 4; j++) rl[rg * 4 + j] = 1.f / (lacc[qt2][rg * 4 + j] + lv[j]);
            }
            size_t rb = (size_t)(b * 4096 + qblk * 128 + qh * 64 + qt2 * 32);
            #pragma unroll
            for (int nt = 0; nt < 4; nt++)
                #pragma unroll
                for (int rg = 0; rg < 2; rg++) {
                    u16x8 pk = *(const u16x8*)(smem + qh * 16384 + qt2 * 8192 + nt * 2048 + rg * 1024 + ln * 16);
                    #pragma unroll
                    for (int j = 0; j < 8; j++) {
                        int r = rg * 8 + j;
                        float val = (Oacc[qt2][nt][r] + bf2f(pk[j])) * rl[r];
                        int row = (r & 3) + 8 * (r >> 2) + 4 * h;
                        Oa[(rb + row) * 256 + oh * 128 + nt * 32 + l31] = f2bf(val);
                    }
                }
        }
    }
}

// ---------------- launch ----------------
extern "C" void kernel_launch(void* const* d_in, const int* in_sizes, int n_in,
                              void* d_out, int out_size, void* d_ws, size_t ws_size,
                              hipStream_t stream) {
    const float* x  = (const float*)d_in[0];
    const float* nw = (const float*)d_in[1];
    const float* nb = (const float*)d_in[2];
    const float* wq = (const float*)d_in[3];
    const float* wk = (const float*)d_in[4];
    const float* wv = (const float*)d_in[5];
    const float* wp = (const float*)d_in[6];
    const float* gm = (const float*)d_in[7];

    char* p = (char*)d_ws;
    unsigned short* ht  = (unsigned short*)p; p += (size_t)32768 * 256 * 2;  // 16 MB
    unsigned short* qk  = (unsigned short*)p; p += (size_t)32768 * 64 * 2;   // 4 MB
    unsigned short* vt  = (unsigned short*)p; p += (size_t)8 * 256 * 4096 * 2; // 16 MB
    unsigned short* oa  = (unsigned short*)p; p += (size_t)32768 * 256 * 2;  // 16 MB
    unsigned short* bqk = (unsigned short*)p; p += 64 * 256 * 2;
    unsigned short* bv  = (unsigned short*)p; p += 256 * 256 * 2;
    unsigned short* bp  = (unsigned short*)p; p += 256 * 256 * 2;

    k_pack<<<dim3(256), dim3(256), 0, stream>>>(wq, wk, wv, wp, bqk, bv, bp);
    k_gnorm<<<dim3(256), dim3(1024), 0, stream>>>(x, nw, nb, ht);
    k_gemm<0><<<dim3(256, 1), dim3(256), 0, stream>>>(ht, bqk, (void*)qk, nullptr, nullptr, 64);
    k_gemm<1><<<dim3(256, 4), dim3(256), 0, stream>>>(ht, bv, (void*)vt, nullptr, nullptr, 0);
    k_flash<<<dim3(512), dim3(256), 0, stream>>>(qk, vt, oa);
    k_gemm<2><<<dim3(256, 4), dim3(256), 0, stream>>>(oa, bp, d_out, x, gm, 0);
}

// Round 8
// 231.743 us; speedup vs baseline: 2.5146x; 1.0887x over previous
//
#include <hip/hip_runtime.h>
#include <cstdint>

// Shapes: B=8, C=256, H=W=64 -> N=4096, d=32, groups=32 (8 ch/group)

typedef __bf16 bf16x8 __attribute__((ext_vector_type(8)));
typedef float f32x4 __attribute__((ext_vector_type(4)));
typedef float f32x16 __attribute__((ext_vector_type(16)));
typedef unsigned int u32x4 __attribute__((ext_vector_type(4)));
typedef unsigned short u16x4 __attribute__((ext_vector_type(4)));
typedef unsigned short u16x8 __attribute__((ext_vector_type(8)));

#define DEVI __device__ __forceinline__

DEVI unsigned short f2bf(float f) {
    __bf16 h = (__bf16)f;               // RNE fptrunc
    return __builtin_bit_cast(unsigned short, h);
}
DEVI float bf2f(unsigned short u) {
    unsigned int x = ((unsigned int)u) << 16;
    return __builtin_bit_cast(float, x);
}

DEVI f32x4 mfma16(bf16x8 a, bf16x8 b, f32x4 c) {
    return __builtin_amdgcn_mfma_f32_16x16x32_bf16(a, b, c, 0, 0, 0);
}
DEVI f32x16 mfma32(bf16x8 a, bf16x8 b, f32x16 c) {
    return __builtin_amdgcn_mfma_f32_32x32x16_bf16(a, b, c, 0, 0, 0);
}

// async global->LDS, 16B per lane, wave-uniform LDS base + lane*16
DEVI void glds16(const unsigned short* g, unsigned short* l) {
    const __attribute__((address_space(1))) unsigned int* gp =
        reinterpret_cast<const __attribute__((address_space(1))) unsigned int*>(
            reinterpret_cast<uintptr_t>(g));
    __attribute__((address_space(3))) unsigned int* lp =
        reinterpret_cast<__attribute__((address_space(3))) unsigned int*>(
            reinterpret_cast<uintptr_t>(l));
    __builtin_amdgcn_global_load_lds(gp, lp, 16, 0, 0);
}

// raw barrier without the compiler's vmcnt(0)-drain; manual waits only
DEVI void barrier_raw() {
    asm volatile("" ::: "memory");
    __builtin_amdgcn_s_barrier();
    asm volatile("" ::: "memory");
}
DEVI void wait_vm0() {
    // SIMM16: vmcnt[3:0]=0, expcnt[6:4]=7, lgkmcnt[13:8]=0x3F, vmcnt[5:4]=0
    __builtin_amdgcn_s_waitcnt(0x3F70);
}

// log2(e)/sqrt(32): folded into Wq so S exits QK-MFMA in exp2 domain
#define QSCALE 0.2550663133f
#define MFIX   12.0f

// ---------------- weight pack fp32 -> bf16 ----------------
__global__ __launch_bounds__(256) void k_pack(
        const float* __restrict__ wq, const float* __restrict__ wk,
        const float* __restrict__ wv, const float* __restrict__ wp,
        unsigned short* __restrict__ bqk, unsigned short* __restrict__ bv,
        unsigned short* __restrict__ bp) {
    int i = blockIdx.x * 256 + threadIdx.x;        // grid 256 -> 65536 threads
    if (i < 8192)       bqk[i] = f2bf(wq[i] * QSCALE);   // rows 0..31 = Wq (pre-scaled)
    else if (i < 16384) bqk[i] = f2bf(wk[i - 8192]);     // rows 32..63 = Wk
    bv[i] = f2bf(wv[i]);
    bp[i] = f2bf(wp[i]);
}

// ---------------- group norm -> h^T (B*N, C) bf16 ----------------
__global__ __launch_bounds__(1024) void k_gnorm(
        const float* __restrict__ x, const float* __restrict__ gw,
        const float* __restrict__ gb, unsigned short* __restrict__ ht) {
    int bg = blockIdx.x;               // 256 blocks = 8 batches * 32 groups
    int b = bg >> 5, g = bg & 31;
    const float* xb = x + ((size_t)(b * 256 + g * 8)) * 4096;  // 8 contiguous rows
    int t = threadIdx.x;
    float s1 = 0.f, s2 = 0.f;
    const f32x4* xv4 = (const f32x4*)xb;
    for (int i = t; i < 8192; i += 1024) {
        f32x4 v = xv4[i];
        #pragma unroll
        for (int j = 0; j < 4; j++) { s1 += v[j]; s2 += v[j] * v[j]; }
    }
    #pragma unroll
    for (int off = 1; off < 64; off <<= 1) {
        s1 += __shfl_xor(s1, off);
        s2 += __shfl_xor(s2, off);
    }
    __shared__ float red[34];
    int wv_ = t >> 6;
    if ((t & 63) == 0) { red[wv_ * 2] = s1; red[wv_ * 2 + 1] = s2; }
    __syncthreads();
    if (t == 0) {
        float a = 0.f, q = 0.f;
        #pragma unroll
        for (int i = 0; i < 16; i++) { a += red[i * 2]; q += red[i * 2 + 1]; }
        float mean = a * (1.f / 32768.f);
        float var = q * (1.f / 32768.f) - mean * mean;
        red[32] = mean; red[33] = rsqrtf(var + 1e-5f);
    }
    __syncthreads();
    float mean = red[32], rstd = red[33];
    float wv8[8], bv8[8];
    #pragma unroll
    for (int c = 0; c < 8; c++) { wv8[c] = gw[g * 8 + c] * rstd; bv8[c] = gb[g * 8 + c] - mean * rstd * gw[g * 8 + c]; }
    int n0 = t * 4;
    f32x4 cv[8];
    #pragma unroll
    for (int c = 0; c < 8; c++) cv[c] = *(const f32x4*)(xb + c * 4096 + n0);
    #pragma unroll
    for (int j = 0; j < 4; j++) {
        u16x8 pk;
        #pragma unroll
        for (int c = 0; c < 8; c++) pk[c] = f2bf(cv[c][j] * wv8[c] + bv8[c]);
        *(u16x8*)(&ht[((size_t)(b * 4096 + n0 + j)) * 256 + g * 8]) = pk;  // 16B store
    }
}

// ---------------- GEMM  C[M x Ncols] = A[M x 256] * Bw[Ncols x 256]^T ----------------
// EPI 0: bf16 row-major out (ldout).  EPI 1: bf16 transposed Vt[b][o][n] with
//        key-dim bit2<->bit3 swap per 16-group (PV A-frag permutation).
// EPI 2: fp32 transposed + residual: out[b][o][n] = x + gamma*acc.
template <int EPI>
__global__ __launch_bounds__(256) void k_gemm(
        const unsigned short* __restrict__ A, const unsigned short* __restrict__ Bw,
        void* __restrict__ outp, const float* __restrict__ xres,
        const float* __restrict__ gamma, int ldout) {
    __shared__ unsigned short lA[128 * 72];
    __shared__ unsigned short lB[64 * 72];
    int t = threadIdx.x;
    int m0 = blockIdx.x * 128, n0 = blockIdx.y * 64;
    int w = t >> 6, lane = t & 63, l15 = lane & 15, quad = lane >> 4;
    f32x4 z4 = {0.f, 0.f, 0.f, 0.f};
    f32x4 acc[2][4];
    #pragma unroll
    for (int i = 0; i < 2; i++)
        #pragma unroll
        for (int j = 0; j < 4; j++) acc[i][j] = z4;

    for (int kb = 0; kb < 4; kb++) {
        #pragma unroll
        for (int i = 0; i < 4; i++) {
            int ch = i * 256 + t;
            int row = ch >> 3, col = (ch & 7) * 8;
            u32x4 v = *(const u32x4*)(A + (size_t)(m0 + row) * 256 + kb * 64 + col);
            *(u32x4*)(&lA[row * 72 + col]) = v;
        }
        #pragma unroll
        for (int i = 0; i < 2; i++) {
            int ch = i * 256 + t;
            int row = ch >> 3, col = (ch & 7) * 8;
            u32x4 v = *(const u32x4*)(Bw + (size_t)(n0 + row) * 256 + kb * 64 + col);
            *(u32x4*)(&lB[row * 72 + col]) = v;
        }
        __syncthreads();
        #pragma unroll
        for (int ks = 0; ks < 2; ks++) {
            bf16x8 af[2], bfr[4];
            #pragma unroll
            for (int fr = 0; fr < 2; fr++)
                af[fr] = *(const bf16x8*)(&lA[(w * 32 + fr * 16 + l15) * 72 + ks * 32 + quad * 8]);
            #pragma unroll
            for (int fn = 0; fn < 4; fn++)
                bfr[fn] = *(const bf16x8*)(&lB[(fn * 16 + l15) * 72 + ks * 32 + quad * 8]);
            #pragma unroll
            for (int fr = 0; fr < 2; fr++)
                #pragma unroll
                for (int fn = 0; fn < 4; fn++)
                    acc[fr][fn] = mfma16(af[fr], bfr[fn], acc[fr][fn]);
        }
        __syncthreads();
    }

    if (EPI == 0) {
        unsigned short* out = (unsigned short*)outp;
        #pragma unroll
        for (int fr = 0; fr < 2; fr++)
            #pragma unroll
            for (int fn = 0; fn < 4; fn++)
                #pragma unroll
                for (int r = 0; r < 4; r++) {
                    int m = m0 + w * 32 + fr * 16 + quad * 4 + r;
                    int n = n0 + fn * 16 + l15;
                    out[(size_t)m * ldout + n] = f2bf(acc[fr][fn][r]);
                }
    } else if (EPI == 1) {
        unsigned short* out = (unsigned short*)outp;
        int b = m0 >> 12, nb = (m0 & 4095) + w * 32;
        int swq = ((quad & 1) << 1) | (quad >> 1);   // bit2<->bit3 swap of n within 16
        #pragma unroll
        for (int fr = 0; fr < 2; fr++)
            #pragma unroll
            for (int fn = 0; fn < 4; fn++) {
                int o = n0 + fn * 16 + l15;
                int n = nb + fr * 16 + swq * 4;
                u16x4 pk;
                #pragma unroll
                for (int r = 0; r < 4; r++) pk[r] = f2bf(acc[fr][fn][r]);
                *(u16x4*)(&out[(((size_t)(b * 256 + o)) << 12) + n]) = pk;
            }
    } else {
        float* out = (float*)outp;
        float gm = gamma[0];
        int b = m0 >> 12, nb = (m0 & 4095) + w * 32;
        #pragma unroll
        for (int fr = 0; fr < 2; fr++)
            #pragma unroll
            for (int fn = 0; fn < 4; fn++) {
                int o = n0 + fn * 16 + l15;
                int n = nb + fr * 16 + quad * 4;
                size_t base = (((size_t)(b * 256 + o)) << 12) + n;
                f32x4 xv = *(const f32x4*)(xres + base);
                f32x4 ov;
                #pragma unroll
                for (int r = 0; r < 4; r++) ov[r] = xv[r] + gm * acc[fr][fn][r];
                *(f32x4*)(out + base) = ov;
            }
    }
}

// ---------------- flash attention: 32x32 MFMA, dbuf, q x2 reg-block, o-split,
//                  VALU rowsum, 2 blocks/CU ----------------
// QK: (B*N, 64) bf16 (q cols 0..31 pre-scaled, k cols 32..63).
// Vt: (B, 256, N) bf16, key-dim sigma-permuted (bit2<->bit3 per 16-group).
// Grid 512 = 8 b x 32 qblk(128q) x 2 oh(128 o-chans). 4 waves = 2 qh x 2 kh.
// Accumulators: Oacc[2][4] (128) + lsum[2] (2) -> total regs <= 256/wave so
// TWO blocks co-reside per CU (2 waves/SIMD): MFMA overlaps the other wave's
// exp2/cvt VALU (m114). Rowsum is per-lane VALU (QK D-layout: lane=q,
// regs=keys) + one shfl_xor(32) at the end — no ones-MFMA, no 32-reg lacc.
__global__ __launch_bounds__(256, 2) void k_flash(
        const unsigned short* __restrict__ QK, const unsigned short* __restrict__ Vt,
        unsigned short* __restrict__ Oa) {
    __shared__ __align__(16) char smem[40960];   // dbuf 2 x (4KB K + 16KB V); epilogue reuse
    int id = blockIdx.x;
    int b = id & 7;                    // batch <-> XCD affinity
    int r3 = id >> 3;
    int oh = r3 & 1, qblk = r3 >> 1;   // o-half, q-block(128)
    int t = threadIdx.x, w = t >> 6, ln = t & 63;
    int l31 = ln & 31, h = ln >> 5;
    int qh = w >> 1, kh = w & 1;
    int q0 = qblk * 128 + qh * 64;     // this wave's 64-q range (2 tiles of 32)

    // persistent Q B-frags: B[k=d][n=q]; lane: q=l31, d = s*16 + h*8 + j
    bf16x8 qb0[2], qb1[2];
    #pragma unroll
    for (int qt2 = 0; qt2 < 2; qt2++) {
        const unsigned short* qrow = QK + ((size_t)(b * 4096 + q0 + qt2 * 32 + l31)) * 64;
        qb0[qt2] = *(const bf16x8*)(qrow + h * 8);
        qb1[qt2] = *(const bf16x8*)(qrow + 16 + h * 8);
    }

    // staging: K tile (wave w stages keys w*16..+16), chunk-swizzled for A-frag reads
    int cgK = (ln & 3) ^ ((ln >> 2) & 3) ^ ((ln >> 4) & 3);
    const unsigned short* gK = QK + ((size_t)(b * 4096 + w * 16 + (ln >> 2))) * 64 + 32 + cgK * 8;
    // V half-tile: wave w stages o-rows oh*128 + w*32..+32, chunk-swizzled
    int vc8 = (ln & 7) ^ ((ln >> 3) & 7);
    const unsigned short* gV = Vt + (((size_t)(b * 256 + oh * 128 + w * 32 + (ln >> 3))) << 12) + vc8 * 8;

    // double buffers: K 4KB + V 16KB each
    unsigned short* lK0 = (unsigned short*)smem;
    unsigned short* lV0 = (unsigned short*)(smem + 4096);
    unsigned short* lK1 = (unsigned short*)(smem + 20480);
    unsigned short* lV1 = (unsigned short*)(smem + 24576);
    unsigned short* sK0 = lK0 + w * 512;
    unsigned short* sV0 = lV0 + w * 2048;
    unsigned short* sK1 = lK1 + w * 512;
    unsigned short* sV1 = lV1 + w * 2048;

    f32x16 z16;
    #pragma unroll
    for (int i = 0; i < 16; i++) z16[i] = 0.f;
    f32x16 minit;
    #pragma unroll
    for (int i = 0; i < 16; i++) minit[i] = -MFIX;
    f32x16 Oacc[2][4];
    #pragma unroll
    for (int qt2 = 0; qt2 < 2; qt2++)
        #pragma unroll
        for (int i = 0; i < 4; i++) Oacc[qt2][i] = z16;
    float lsum[2] = {0.f, 0.f};        // per-lane partial rowsum (q=l31, this h's keys)

    // loop-invariant LDS read offsets
    int gl = (l31 & 3) ^ ((l31 >> 2) & 3);
    const unsigned short* kf0p0 = lK0 + (kh * 32 + l31) * 32 + ((0 + h) ^ gl) * 8;
    const unsigned short* kf1p0 = lK0 + (kh * 32 + l31) * 32 + ((2 + h) ^ gl) * 8;
    const unsigned short* kf0p1 = lK1 + (kh * 32 + l31) * 32 + ((0 + h) ^ gl) * 8;
    const unsigned short* kf1p1 = lK1 + (kh * 32 + l31) * 32 + ((2 + h) ^ gl) * 8;
    int slotA = ((kh * 4 + 0 * 2 + h) ^ (ln & 7)) * 8;
    int slotB = ((kh * 4 + 1 * 2 + h) ^ (ln & 7)) * 8;

    auto stage = [&](int kn, unsigned short* sK, unsigned short* sV) {
        glds16(gK + (size_t)kn * 4096, sK);
        #pragma unroll
        for (int j = 0; j < 4; j++)
            glds16(gV + ((size_t)j * 8 << 12) + kn * 64, sV + j * 512);
    };

    auto compute = [&](const unsigned short* kf0p, const unsigned short* kf1p,
                       const unsigned short* lV) {
        bf16x8 kf0 = *(const bf16x8*)kf0p;
        bf16x8 kf1 = *(const bf16x8*)kf1p;
        bf16x8 pa[2][2];
        #pragma unroll
        for (int qt2 = 0; qt2 < 2; qt2++) {
            f32x16 St = mfma32(kf0, qb0[qt2], minit);
            St = mfma32(kf1, qb1[qt2], St);
            u16x8 p0u, p1u;
            float s = 0.f;
            #pragma unroll
            for (int j = 0; j < 8; j++) {
                float e0 = __builtin_amdgcn_exp2f(St[j]);
                float e1 = __builtin_amdgcn_exp2f(St[8 + j]);
                s += e0 + e1;                       // rowsum in VALU (lane=q, regs=keys)
                p0u[j] = f2bf(e0);
                p1u[j] = f2bf(e1);
            }
            lsum[qt2] += s;
            pa[qt2][0] = __builtin_bit_cast(bf16x8, p0u);
            pa[qt2][1] = __builtin_bit_cast(bf16x8, p1u);
        }
        #pragma unroll
        for (int nt = 0; nt < 4; nt++) {
            bf16x8 vf = *(const bf16x8*)(lV + (nt * 32 + l31) * 64 + slotA);
            Oacc[0][nt] = mfma32(pa[0][0], vf, Oacc[0][nt]);
            Oacc[1][nt] = mfma32(pa[1][0], vf, Oacc[1][nt]);
        }
        #pragma unroll
        for (int nt = 0; nt < 4; nt++) {
            bf16x8 vf = *(const bf16x8*)(lV + (nt * 32 + l31) * 64 + slotB);
            Oacc[0][nt] = mfma32(pa[0][1], vf, Oacc[0][nt]);
            Oacc[1][nt] = mfma32(pa[1][1], vf, Oacc[1][nt]);
        }
    };

    stage(0, sK0, sV0);                 // preload tile 0 into buf0
    for (int kt = 0; kt < 64; kt += 2) {
        // --- even tile: compute buf0, prefetch kt+1 into buf1 ---
        wait_vm0();                     // drain buf0's loads (issued 1 iter ago)
        barrier_raw();
        stage(kt + 1, sK1, sV1);
        compute(kf0p0, kf1p0, lV0);
        // --- odd tile: compute buf1, prefetch kt+2 into buf0 ---
        wait_vm0();
        barrier_raw();
        if (kt + 2 < 64) stage(kt + 2, sK0, sV0);
        compute(kf0p1, kf1p1, lV1);
    }
    // finish rowsums: combine the two h-halves (lane l31 and l31+32 hold
    // complementary key subsets for the same q)
    #pragma unroll
    for (int qt2 = 0; qt2 < 2; qt2++) lsum[qt2] += __shfl_xor(lsum[qt2], 32);
    __syncthreads();                    // all LDS reads done before smem reuse

    // ---- epilogue via smem reuse ----
    float* sf = (float*)smem;
    // lsum publish: [8192 + qh*64 + qt2*32 + q] (kh1), [8320 + ...] (kh0)
    int lbase = (kh ? 8192 : 8320) + qh * 64 + l31;
    sf[lbase] = lsum[0];
    sf[lbase + 32] = lsum[1];
    if (kh == 1) {                      // publish O partials (bf16)
        #pragma unroll
        for (int qt2 = 0; qt2 < 2; qt2++)
            #pragma unroll
            for (int nt = 0; nt < 4; nt++)
                #pragma unroll
                for (int rg = 0; rg < 2; rg++) {
                    u16x8 pk;
                    #pragma unroll
                    for (int j = 0; j < 8; j++) pk[j] = f2bf(Oacc[qt2][nt][rg * 8 + j]);
                    *(u16x8*)(smem + qh * 16384 + qt2 * 8192 + nt * 2048 + rg * 1024 + ln * 16) = pk;
                }
    }
    __syncthreads();
    if (kh == 0) {                      // reduce + normalize + store
        #pragma unroll
        for (int qt2 = 0; qt2 < 2; qt2++) {
            float rl[16];
            #pragma unroll
            for (int r = 0; r < 16; r++) {
                int row = (r & 3) + 8 * (r >> 2) + 4 * h;
                float l = sf[8192 + qh * 64 + qt2 * 32 + row] +
                          sf[8320 + qh * 64 + qt2 * 32 + row];
                rl[r] = 1.f / l;
            }
            size_t rb = (size_t)(b * 4096 + qblk * 128 + qh * 64 + qt2 * 32);
            #pragma unroll
            for (int nt = 0; nt < 4; nt++)
                #pragma unroll
                for (int rg = 0; rg < 2; rg++) {
                    u16x8 pk = *(const u16x8*)(smem + qh * 16384 + qt2 * 8192 + nt * 2048 + rg * 1024 + ln * 16);
                    #pragma unroll
                    for (int j = 0; j < 8; j++) {
                        int r = rg * 8 + j;
                        float val = (Oacc[qt2][nt][r] + bf2f(pk[j])) * rl[r];
                        int row = (r & 3) + 8 * (r >> 2) + 4 * h;
                        Oa[(rb + row) * 256 + oh * 128 + nt * 32 + l31] = f2bf(val);
                    }
                }
        }
    }
}

// ---------------- launch ----------------
extern "C" void kernel_launch(void* const* d_in, const int* in_sizes, int n_in,
                              void* d_out, int out_size, void* d_ws, size_t ws_size,
                              hipStream_t stream) {
    const float* x  = (const float*)d_in[0];
    const float* nw = (const float*)d_in[1];
    const float* nb = (const float*)d_in[2];
    const float* wq = (const float*)d_in[3];
    const float* wk = (const float*)d_in[4];
    const float* wv = (const float*)d_in[5];
    const float* wp = (const float*)d_in[6];
    const float* gm = (const float*)d_in[7];

    char* p = (char*)d_ws;
    unsigned short* ht  = (unsigned short*)p; p += (size_t)32768 * 256 * 2;  // 16 MB
    unsigned short* qk  = (unsigned short*)p; p += (size_t)32768 * 64 * 2;   // 4 MB
    unsigned short* vt  = (unsigned short*)p; p += (size_t)8 * 256 * 4096 * 2; // 16 MB
    unsigned short* oa  = (unsigned short*)p; p += (size_t)32768 * 256 * 2;  // 16 MB
    unsigned short* bqk = (unsigned short*)p; p += 64 * 256 * 2;
    unsigned short* bv  = (unsigned short*)p; p += 256 * 256 * 2;
    unsigned short* bp  = (unsigned short*)p; p += 256 * 256 * 2;

    k_pack<<<dim3(256), dim3(256), 0, stream>>>(wq, wk, wv, wp, bqk, bv, bp);
    k_gnorm<<<dim3(256), dim3(1024), 0, stream>>>(x, nw, nb, ht);
    k_gemm<0><<<dim3(256, 1), dim3(256), 0, stream>>>(ht, bqk, (void*)qk, nullptr, nullptr, 64);
    k_gemm<1><<<dim3(256, 4), dim3(256), 0, stream>>>(ht, bv, (void*)vt, nullptr, nullptr, 0);
    k_flash<<<dim3(512), dim3(256), 0, stream>>>(qk, vt, oa);
    k_gemm<2><<<dim3(256, 4), dim3(256), 0, stream>>>(oa, bp, d_out, x, gm, 0);
}